// Round 12
// baseline (203.435 us; speedup 1.0000x reference)
//
#include <hip/hip_runtime.h>
#include <cstdint>

#define DM   1024
#define NH   16
#define DKd  64
#define Bb   4
#define Ss   2048

using bf16x8_t = __attribute__((ext_vector_type(8))) __bf16;
using bf16x2_t = __attribute__((ext_vector_type(2))) __bf16;
using f32x4_t  = __attribute__((ext_vector_type(4))) float;
using u16x4_t  = __attribute__((ext_vector_type(4))) unsigned short;
using u16x8_t  = __attribute__((ext_vector_type(8))) unsigned short;
using u32x2_t  = __attribute__((ext_vector_type(2))) unsigned int;

#define MFMA16(a, b, c) __builtin_amdgcn_mfma_f32_16x16x32_bf16((a), (b), (c), 0, 0, 0)

// 16x16x16 bf16 MFMA via inline asm. D==C accumulate chain.
__device__ __forceinline__ void mfma_k16(f32x4_t& c, u32x2_t a, u32x2_t b) {
  asm("v_mfma_f32_16x16x16_bf16 %0, %1, %2, %0" : "+v"(c) : "v"(a), "v"(b));
}

__device__ __forceinline__ unsigned short f2bf(float f) {
  union { float f; unsigned u; } v; v.f = f;
  unsigned r = v.u + 0x7fffu + ((v.u >> 16) & 1u);
  return (unsigned short)(r >> 16);
}

__device__ __forceinline__ void gl16(const void* g, void* l) {
  __builtin_amdgcn_global_load_lds(
      (const __attribute__((address_space(1))) void*)g,
      (__attribute__((address_space(3))) void*)l, 16, 0, 0);
}

// ---------------- f32 -> bf16 conversion (q,k,v + 4 weights) -----------------
struct CvtArgs {
  const float* src[8];
  unsigned short* dst[8];
  int n[8];
};

__global__ void cvt_kernel(CvtArgs a) {
  const int seg = blockIdx.y;
  const float* __restrict__ s = a.src[seg];
  unsigned short* __restrict__ d = a.dst[seg];
  const int n = a.n[seg];
  const int step = gridDim.x * blockDim.x * 8;
  for (int i = (blockIdx.x * blockDim.x + threadIdx.x) * 8; i < n; i += step) {
    f32x4_t v0 = *(const f32x4_t*)(s + i);
    f32x4_t v1 = *(const f32x4_t*)(s + i + 4);
    u16x8_t r;
#pragma unroll
    for (int j = 0; j < 4; ++j) {
      r[j]     = f2bf(v0[j]);
      r[4 + j] = f2bf(v1[j]);
    }
    *(u16x8_t*)(d + i) = r;
  }
}

struct GemmArgs {
  const unsigned short* A[3];
  const unsigned short* W[3];
  const float* bias[3];
  void* out[3];
  float scl[3];
  int epi[3];
};

// Shared epilogue: epi 0 -> bf16 [B,H,S,64] (scaled); epi 1 -> f32 [M,N];
// epi 2 -> bf16 [B,H,64,S] (V^T).
__device__ __forceinline__ void gemm_epilogue(
    const GemmArgs& ga, int z, int epi, float scl, const float* bias,
    f32x4_t (&acc)[4][4], int m0, int n0, int wm, int wn, int qr, int kg) {
#pragma unroll
  for (int ni = 0; ni < 4; ++ni) {
    const int col = n0 + wn * 64 + ni * 16 + qr;
    const float bi = bias[col];
#pragma unroll
    for (int mi = 0; mi < 4; ++mi) {
      const int mb = m0 + wm * 64 + mi * 16 + kg * 4;
      float vv[4];
#pragma unroll
      for (int j = 0; j < 4; ++j) vv[j] = (acc[mi][ni][j] + bi) * scl;
      if (epi == 0) {
        unsigned short* O = (unsigned short*)ga.out[z];
#pragma unroll
        for (int j = 0; j < 4; ++j) {
          const int m = mb + j;
          O[(size_t)((m >> 11) * NH + (col >> 6)) * (Ss * DKd) +
            (size_t)(m & (Ss - 1)) * DKd + (col & 63)] = f2bf(vv[j]);
        }
      } else if (epi == 2) {
        unsigned short* O = (unsigned short*)ga.out[z];
        u16x4_t r;
#pragma unroll
        for (int j = 0; j < 4; ++j) r[j] = f2bf(vv[j]);
        const int b = mb >> 11, s = mb & (Ss - 1);
        *(u16x4_t*)&O[((size_t)(b * NH + (col >> 6)) * DKd + (col & 63)) * Ss + s] = r;
      } else {
        float* O = (float*)ga.out[z];
#pragma unroll
        for (int j = 0; j < 4; ++j) O[(size_t)(mb + j) * 1024 + col] = vv[j];
      }
    }
  }
}

// ---------------- bf16 GEMM: BK=64, XOR-swizzled both-sides ------------------
__global__ __launch_bounds__(256, 4) void gemm_bt(GemmArgs ga) {
  const int L = blockIdx.x + 8 * (blockIdx.y + 64 * blockIdx.z);
  const int xcd = L & 7;
  const int sidx = L >> 3;
  const int xw = sidx & 7;
  const int grp = sidx >> 3;
  const int z = grp >> 3;
  const int yw = (grp & 7) * 8 + xcd;

  const unsigned short* __restrict__ A = ga.A[z];
  const unsigned short* __restrict__ W = ga.W[z];
  const float* __restrict__ bias = ga.bias[z];
  const float scl = ga.scl[z];
  const int epi = ga.epi[z];

  __shared__ __align__(16) unsigned short sA[128 * 64];  // 16 KB
  __shared__ __align__(16) unsigned short sB[128 * 64];  // 16 KB

  const int tid  = threadIdx.x;
  const int lane = tid & 63;
  const int wid  = tid >> 6;
  const int wm   = wid >> 1, wn = wid & 1;
  const int m0 = yw * 128, n0 = xw * 128;
  const int qr = lane & 15, kg = lane >> 4;

  const int arow = tid >> 3;
  const int aswz = (tid & 7) ^ ((tid >> 3) & 7);

  f32x4_t acc[4][4];
#pragma unroll
  for (int mi = 0; mi < 4; ++mi)
#pragma unroll
    for (int ni = 0; ni < 4; ++ni) acc[mi][ni] = {0.f, 0.f, 0.f, 0.f};

  for (int kt = 0; kt < 16; ++kt) {
    const int k0 = kt * 64;
#pragma unroll
    for (int j = 0; j < 4; ++j) {
      gl16(A + (size_t)(m0 + arow + j * 32) * 1024 + k0 + aswz * 8,
           &sA[tid * 8 + j * 2048]);
      gl16(W + (size_t)(n0 + arow + j * 32) * 1024 + k0 + aswz * 8,
           &sB[tid * 8 + j * 2048]);
    }
    __syncthreads();

#pragma unroll
    for (int kk = 0; kk < 2; ++kk) {
      bf16x8_t af[4], bfr[4];
#pragma unroll
      for (int i = 0; i < 4; ++i) {
        const int slot = ((kk * 4 + kg) ^ (qr & 7)) * 8;
        af[i]  = *(const bf16x8_t*)&sA[(wm * 64 + i * 16 + qr) * 64 + slot];
        bfr[i] = *(const bf16x8_t*)&sB[(wn * 64 + i * 16 + qr) * 64 + slot];
      }
      __builtin_amdgcn_s_setprio(1);
#pragma unroll
      for (int mi = 0; mi < 4; ++mi)
#pragma unroll
        for (int ni = 0; ni < 4; ++ni)
          acc[mi][ni] = MFMA16(af[mi], bfr[ni], acc[mi][ni]);
      __builtin_amdgcn_s_setprio(0);
    }
    __syncthreads();
  }

  gemm_epilogue(ga, z, epi, scl, bias, acc, m0, n0, wm, wn, qr, kg);
}

// ---------------- causal flash attention, Dk=64, QBLK=128, unpaired ---------
// Grid (8,128): 1024 blocks = 4 blocks/CU (was 2 -> VALU idle 50%).
// x = XCD, bh = x*8+(y&7) keeps 8 heads per XCD L2-resident.
// jsub = 15-(y>>3): longest blocks (32 kv-tiles) dispatch first.
__global__ __launch_bounds__(256, 4) void attn_kernel(
    const unsigned short* __restrict__ Qp, const unsigned short* __restrict__ Kp,
    const unsigned short* __restrict__ Vt, unsigned short* __restrict__ X) {
  const int x = blockIdx.x, y = blockIdx.y;
  const int bh = x * 8 + (y & 7);
  const int jsub = 15 - (y >> 3);

  const int tid = threadIdx.x, lane = tid & 63, w = tid >> 6;
  const int qr = lane & 15, kg = lane >> 4;

  const unsigned short* Qb = Qp + (size_t)bh * Ss * DKd;
  const unsigned short* Kb = Kp + (size_t)bh * Ss * DKd;
  const unsigned short* Vb = Vt + (size_t)bh * Ss * DKd;  // [64][2048]

  __shared__ __align__(16) unsigned short kbuf[2][4096];
  __shared__ __align__(16) unsigned short vbuf[2][4096];

  const int R0 = tid >> 3, c80 = (tid & 7) ^ (R0 & 7);
  const int R1 = R0 + 32,  c81 = (tid & 7) ^ (R1 & 7);

  const int bq = bh >> 4, hh = bh & 15;

  const int qbase = jsub * 128;
  const int ntile = 2 * jsub + 2;
  const int qrowA = qbase + w * 32 + qr;
  const int qrowB = qrowA + 16;

  const bf16x8_t qfA0 = *(const bf16x8_t*)&Qb[(size_t)qrowA * DKd + kg * 8];
  const bf16x8_t qfA1 = *(const bf16x8_t*)&Qb[(size_t)qrowA * DKd + 32 + kg * 8];
  const bf16x8_t qfB0 = *(const bf16x8_t*)&Qb[(size_t)qrowB * DKd + kg * 8];
  const bf16x8_t qfB1 = *(const bf16x8_t*)&Qb[(size_t)qrowB * DKd + 32 + kg * 8];

  float lA = 0.f, lB = 0.f;
  f32x4_t o[2][4];
#pragma unroll
  for (int g = 0; g < 2; ++g)
#pragma unroll
    for (int nd = 0; nd < 4; ++nd) o[g][nd] = {0.f, 0.f, 0.f, 0.f};

  int cur = 0;
  gl16(Kb + (size_t)R0 * DKd + c80 * 8, &kbuf[0][tid * 8]);
  gl16(Kb + (size_t)R1 * DKd + c81 * 8, &kbuf[0][tid * 8 + 2048]);
  gl16(Vb + (size_t)R0 * Ss + c80 * 8, &vbuf[0][tid * 8]);
  gl16(Vb + (size_t)R1 * Ss + c81 * 8, &vbuf[0][tid * 8 + 2048]);
  __syncthreads();

  for (int t = 0; t < ntile; ++t) {
    if (t + 1 < ntile) {
      const int kv0 = (t + 1) * 64;
      const int nb = cur ^ 1;
      gl16(Kb + (size_t)(kv0 + R0) * DKd + c80 * 8, &kbuf[nb][tid * 8]);
      gl16(Kb + (size_t)(kv0 + R1) * DKd + c81 * 8, &kbuf[nb][tid * 8 + 2048]);
      gl16(Vb + (size_t)R0 * Ss + kv0 + c80 * 8, &vbuf[nb][tid * 8]);
      gl16(Vb + (size_t)R1 * Ss + kv0 + c81 * 8, &vbuf[nb][tid * 8 + 2048]);
    }

    // waves 0,1 are fully future-masked on the block's last tile
    const bool act = !(w < 2 && t == 2 * jsub + 1);
    if (act) {
      // ---- QK^T (swapped): sX[ni][j] = S[q][kv=16ni+4kg+j] - 8 ----
      f32x4_t sA_[4], sB_[4];
#pragma unroll
      for (int ni = 0; ni < 4; ++ni) {
        sA_[ni] = {-8.f, -8.f, -8.f, -8.f};
        sB_[ni] = {-8.f, -8.f, -8.f, -8.f};
      }
      __builtin_amdgcn_s_setprio(1);
#pragma unroll
      for (int ni = 0; ni < 4; ++ni) {
        const int R = ni * 16 + qr;
        const bf16x8_t kf0 =
            *(const bf16x8_t*)&kbuf[cur][(R * 8 + (kg ^ (qr & 7))) * 8];
        const bf16x8_t kf1 =
            *(const bf16x8_t*)&kbuf[cur][(R * 8 + ((4 + kg) ^ (qr & 7))) * 8];
        sA_[ni] = MFMA16(kf0, qfA0, sA_[ni]);
        sA_[ni] = MFMA16(kf1, qfA1, sA_[ni]);
        sB_[ni] = MFMA16(kf0, qfB0, sB_[ni]);
        sB_[ni] = MFMA16(kf1, qfB1, sB_[ni]);
      }
      __builtin_amdgcn_s_setprio(0);

      // ---- causal mask (last two tiles only) ----
      if (t >= 2 * jsub) {
        const int off = (t == 2 * jsub) ? 0 : 64;
        const int rA = w * 32 + qr - off;
#pragma unroll
        for (int ni = 0; ni < 4; ++ni)
#pragma unroll
          for (int j = 0; j < 4; ++j) {
            const int c = ni * 16 + kg * 4 + j;
            if (c > rA) sA_[ni][j] = -1.0e30f;
            if (c > rA + 16) sB_[ni][j] = -1.0e30f;
          }
      }

      // ---- fixed-bias softmax + pack, per group ----
      u32x2_t pbA[4], pbB[4];
#pragma unroll
      for (int ni = 0; ni < 4; ++ni) {
        float pa0 = exp2f(sA_[ni][0]), pa1 = exp2f(sA_[ni][1]);
        float pa2 = exp2f(sA_[ni][2]), pa3 = exp2f(sA_[ni][3]);
        lA += (pa0 + pa1) + (pa2 + pa3);
        bf16x2_t lo, hi;
        lo[0] = (__bf16)pa0; lo[1] = (__bf16)pa1;
        hi[0] = (__bf16)pa2; hi[1] = (__bf16)pa3;
        pbA[ni][0] = __builtin_bit_cast(unsigned, lo);
        pbA[ni][1] = __builtin_bit_cast(unsigned, hi);
        float pb0 = exp2f(sB_[ni][0]), pb1 = exp2f(sB_[ni][1]);
        float pb2 = exp2f(sB_[ni][2]), pb3 = exp2f(sB_[ni][3]);
        lB += (pb0 + pb1) + (pb2 + pb3);
        bf16x2_t lo2, hi2;
        lo2[0] = (__bf16)pb0; lo2[1] = (__bf16)pb1;
        hi2[0] = (__bf16)pb2; hi2[1] = (__bf16)pb3;
        pbB[ni][0] = __builtin_bit_cast(unsigned, lo2);
        pbB[ni][1] = __builtin_bit_cast(unsigned, hi2);
      }
      asm volatile("s_nop 1");  // VALU-write -> MFMA-read hazard guard

      // ---- PV: O^T[d][q] += V^T[d][kv] * P^T[kv][q] (k16 MFMAs) ----
      __builtin_amdgcn_s_setprio(1);
#pragma unroll
      for (int nd = 0; nd < 4; ++nd) {
        const int rb = (qr + 16 * nd) * 64 + 4 * (kg & 1);
        const int ch = kg >> 1, sw = qr & 7;
        u32x2_t va0 = *(const u32x2_t*)&vbuf[cur][rb + 8 * ((ch + 0) ^ sw)];
        u32x2_t va1 = *(const u32x2_t*)&vbuf[cur][rb + 8 * ((ch + 2) ^ sw)];
        u32x2_t va2 = *(const u32x2_t*)&vbuf[cur][rb + 8 * ((ch + 4) ^ sw)];
        u32x2_t va3 = *(const u32x2_t*)&vbuf[cur][rb + 8 * ((ch + 6) ^ sw)];
        mfma_k16(o[0][nd], va0, pbA[0]);
        mfma_k16(o[0][nd], va1, pbA[1]);
        mfma_k16(o[0][nd], va2, pbA[2]);
        mfma_k16(o[0][nd], va3, pbA[3]);
        mfma_k16(o[1][nd], va0, pbB[0]);
        mfma_k16(o[1][nd], va1, pbB[1]);
        mfma_k16(o[1][nd], va2, pbB[2]);
        mfma_k16(o[1][nd], va3, pbB[3]);
      }
      __builtin_amdgcn_s_setprio(0);
    }

    __syncthreads();  // stage(t+1) drained + all reads of buf[cur] done
    cur ^= 1;
  }

  // ---- row-sum reduce + normalize + write both groups ----
  float lsA = lA, lsB = lB;
  lsA += __shfl_xor(lsA, 16); lsA += __shfl_xor(lsA, 32);
  lsB += __shfl_xor(lsB, 16); lsB += __shfl_xor(lsB, 32);
  const float invA = 1.0f / lsA, invB = 1.0f / lsB;
#pragma unroll
  for (int nd = 0; nd < 4; ++nd) {
    u16x4_t rA, rB;
#pragma unroll
    for (int j = 0; j < 4; ++j) {
      rA[j] = f2bf(o[0][nd][j] * invA);
      rB[j] = f2bf(o[1][nd][j] * invB);
    }
    const int d = nd * 16 + kg * 4;
    *(u16x4_t*)&X[(size_t)(bq * Ss + qrowA) * DM + hh * DKd + d] = rA;
    *(u16x4_t*)&X[(size_t)(bq * Ss + qrowB) * DM + hh * DKd + d] = rB;
  }
}

// ---------------- host launch ------------------------------------------------
extern "C" void kernel_launch(void* const* d_in, const int* in_sizes, int n_in,
                              void* d_out, int out_size, void* d_ws, size_t ws_size,
                              hipStream_t stream) {
  const float* q  = (const float*)d_in[0];
  const float* k  = (const float*)d_in[1];
  const float* v  = (const float*)d_in[2];
  const float* Wq = (const float*)d_in[4];
  const float* bq = (const float*)d_in[5];
  const float* Wk = (const float*)d_in[6];
  const float* bk = (const float*)d_in[7];
  const float* Wv = (const float*)d_in[8];
  const float* bv = (const float*)d_in[9];
  const float* Wo = (const float*)d_in[10];
  const float* bo = (const float*)d_in[11];

  const size_t NIN = (size_t)Bb * Ss * DM;
  const size_t NW  = (size_t)DM * DM;

  unsigned short* ws  = (unsigned short*)d_ws;
  unsigned short* Wqb = ws;
  unsigned short* Wkb = Wqb + NW;
  unsigned short* Wvb = Wkb + NW;
  unsigned short* Wob = Wvb + NW;
  unsigned short* qb  = Wob + NW;
  unsigned short* kb  = qb + NIN;
  unsigned short* vb  = kb + NIN;
  unsigned short* Qp  = vb + NIN;
  unsigned short* Kp  = Qp + NIN;
  unsigned short* Vt  = Kp + NIN;
  unsigned short* X   = qb;  // qb dead after projections

  CvtArgs ca{};
  ca.src[0] = q;  ca.dst[0] = qb;  ca.n[0] = (int)NIN;
  ca.src[1] = k;  ca.dst[1] = kb;  ca.n[1] = (int)NIN;
  ca.src[2] = v;  ca.dst[2] = vb;  ca.n[2] = (int)NIN;
  ca.src[3] = Wq; ca.dst[3] = Wqb; ca.n[3] = (int)NW;
  ca.src[4] = Wk; ca.dst[4] = Wkb; ca.n[4] = (int)NW;
  ca.src[5] = Wv; ca.dst[5] = Wvb; ca.n[5] = (int)NW;
  ca.src[6] = Wo; ca.dst[6] = Wob; ca.n[6] = (int)NW;
  cvt_kernel<<<dim3(1024, 7), 256, 0, stream>>>(ca);

  const float SC = 0.18033688011112042f;  // (1/sqrt(64)) * log2(e)

  GemmArgs g1{};
  g1.A[0] = qb;  g1.A[1] = kb;  g1.A[2] = vb;
  g1.W[0] = Wqb; g1.W[1] = Wkb; g1.W[2] = Wvb;
  g1.bias[0] = bq; g1.bias[1] = bk; g1.bias[2] = bv;
  g1.out[0] = Qp;  g1.out[1] = Kp;  g1.out[2] = Vt;
  g1.scl[0] = SC;  g1.scl[1] = 1.f; g1.scl[2] = 1.f;
  g1.epi[0] = 0;   g1.epi[1] = 0;   g1.epi[2] = 2;
  gemm_bt<<<dim3(8, 64, 3), 256, 0, stream>>>(g1);

  attn_kernel<<<dim3(8, 128), 256, 0, stream>>>(Qp, Kp, Vt, X);

  GemmArgs g2{};
  g2.A[0] = X; g2.W[0] = Wob; g2.bias[0] = bo; g2.out[0] = d_out;
  g2.scl[0] = 1.f; g2.epi[0] = 1;
  gemm_bt<<<dim3(8, 64, 1), 256, 0, stream>>>(g2);
}

// Round 13
// 167.697 us; speedup vs baseline: 1.2131x; 1.2131x over previous
//
#include <hip/hip_runtime.h>
#include <cstdint>

#define DM   1024
#define NH   16
#define DKd  64
#define Bb   4
#define Ss   2048

using bf16x8_t = __attribute__((ext_vector_type(8))) __bf16;
using bf16x2_t = __attribute__((ext_vector_type(2))) __bf16;
using f32x4_t  = __attribute__((ext_vector_type(4))) float;
using u16x4_t  = __attribute__((ext_vector_type(4))) unsigned short;
using u16x8_t  = __attribute__((ext_vector_type(8))) unsigned short;
using u32x2_t  = __attribute__((ext_vector_type(2))) unsigned int;

#define MFMA16(a, b, c) __builtin_amdgcn_mfma_f32_16x16x32_bf16((a), (b), (c), 0, 0, 0)

// 16x16x16 bf16 MFMA via inline asm. D==C accumulate chain.
__device__ __forceinline__ void mfma_k16(f32x4_t& c, u32x2_t a, u32x2_t b) {
  asm("v_mfma_f32_16x16x16_bf16 %0, %1, %2, %0" : "+v"(c) : "v"(a), "v"(b));
}

__device__ __forceinline__ unsigned short f2bf(float f) {
  union { float f; unsigned u; } v; v.f = f;
  unsigned r = v.u + 0x7fffu + ((v.u >> 16) & 1u);
  return (unsigned short)(r >> 16);
}

__device__ __forceinline__ void gl16(const void* g, void* l) {
  __builtin_amdgcn_global_load_lds(
      (const __attribute__((address_space(1))) void*)g,
      (__attribute__((address_space(3))) void*)l, 16, 0, 0);
}

// ---------------- f32 -> bf16 conversion (q,k,v + 4 weights) -----------------
struct CvtArgs {
  const float* src[8];
  unsigned short* dst[8];
  int n[8];
};

__global__ void cvt_kernel(CvtArgs a) {
  const int seg = blockIdx.y;
  const float* __restrict__ s = a.src[seg];
  unsigned short* __restrict__ d = a.dst[seg];
  const int n = a.n[seg];
  const int step = gridDim.x * blockDim.x * 8;
  for (int i = (blockIdx.x * blockDim.x + threadIdx.x) * 8; i < n; i += step) {
    f32x4_t v0 = *(const f32x4_t*)(s + i);
    f32x4_t v1 = *(const f32x4_t*)(s + i + 4);
    u16x8_t r;
#pragma unroll
    for (int j = 0; j < 4; ++j) {
      r[j]     = f2bf(v0[j]);
      r[4 + j] = f2bf(v1[j]);
    }
    *(u16x8_t*)(d + i) = r;
  }
}

struct GemmArgs {
  const unsigned short* A[3];
  const unsigned short* W[3];
  const float* bias[3];
  void* out[3];
  float scl[3];
  int epi[3];
};

// Shared epilogue: epi 0 -> bf16 [B,H,S,64] (scaled); epi 1 -> f32 [M,N];
// epi 2 -> bf16 [B,H,64,S] (V^T).
__device__ __forceinline__ void gemm_epilogue(
    const GemmArgs& ga, int z, int epi, float scl, const float* bias,
    f32x4_t (&acc)[4][4], int m0, int n0, int wm, int wn, int qr, int kg) {
#pragma unroll
  for (int ni = 0; ni < 4; ++ni) {
    const int col = n0 + wn * 64 + ni * 16 + qr;
    const float bi = bias[col];
#pragma unroll
    for (int mi = 0; mi < 4; ++mi) {
      const int mb = m0 + wm * 64 + mi * 16 + kg * 4;
      float vv[4];
#pragma unroll
      for (int j = 0; j < 4; ++j) vv[j] = (acc[mi][ni][j] + bi) * scl;
      if (epi == 0) {
        unsigned short* O = (unsigned short*)ga.out[z];
#pragma unroll
        for (int j = 0; j < 4; ++j) {
          const int m = mb + j;
          O[(size_t)((m >> 11) * NH + (col >> 6)) * (Ss * DKd) +
            (size_t)(m & (Ss - 1)) * DKd + (col & 63)] = f2bf(vv[j]);
        }
      } else if (epi == 2) {
        unsigned short* O = (unsigned short*)ga.out[z];
        u16x4_t r;
#pragma unroll
        for (int j = 0; j < 4; ++j) r[j] = f2bf(vv[j]);
        const int b = mb >> 11, s = mb & (Ss - 1);
        *(u16x4_t*)&O[((size_t)(b * NH + (col >> 6)) * DKd + (col & 63)) * Ss + s] = r;
      } else {
        float* O = (float*)ga.out[z];
#pragma unroll
        for (int j = 0; j < 4; ++j) O[(size_t)(mb + j) * 1024 + col] = vv[j];
      }
    }
  }
}

// ---------------- bf16 GEMM: BK=64, XOR-swizzled both-sides ------------------
__global__ __launch_bounds__(256, 4) void gemm_bt(GemmArgs ga) {
  const int L = blockIdx.x + 8 * (blockIdx.y + 64 * blockIdx.z);
  const int xcd = L & 7;
  const int sidx = L >> 3;
  const int xw = sidx & 7;
  const int grp = sidx >> 3;
  const int z = grp >> 3;
  const int yw = (grp & 7) * 8 + xcd;

  const unsigned short* __restrict__ A = ga.A[z];
  const unsigned short* __restrict__ W = ga.W[z];
  const float* __restrict__ bias = ga.bias[z];
  const float scl = ga.scl[z];
  const int epi = ga.epi[z];

  __shared__ __align__(16) unsigned short sA[128 * 64];  // 16 KB
  __shared__ __align__(16) unsigned short sB[128 * 64];  // 16 KB

  const int tid  = threadIdx.x;
  const int lane = tid & 63;
  const int wid  = tid >> 6;
  const int wm   = wid >> 1, wn = wid & 1;
  const int m0 = yw * 128, n0 = xw * 128;
  const int qr = lane & 15, kg = lane >> 4;

  const int arow = tid >> 3;
  const int aswz = (tid & 7) ^ ((tid >> 3) & 7);

  f32x4_t acc[4][4];
#pragma unroll
  for (int mi = 0; mi < 4; ++mi)
#pragma unroll
    for (int ni = 0; ni < 4; ++ni) acc[mi][ni] = {0.f, 0.f, 0.f, 0.f};

  for (int kt = 0; kt < 16; ++kt) {
    const int k0 = kt * 64;
#pragma unroll
    for (int j = 0; j < 4; ++j) {
      gl16(A + (size_t)(m0 + arow + j * 32) * 1024 + k0 + aswz * 8,
           &sA[tid * 8 + j * 2048]);
      gl16(W + (size_t)(n0 + arow + j * 32) * 1024 + k0 + aswz * 8,
           &sB[tid * 8 + j * 2048]);
    }
    __syncthreads();

#pragma unroll
    for (int kk = 0; kk < 2; ++kk) {
      bf16x8_t af[4], bfr[4];
#pragma unroll
      for (int i = 0; i < 4; ++i) {
        const int slot = ((kk * 4 + kg) ^ (qr & 7)) * 8;
        af[i]  = *(const bf16x8_t*)&sA[(wm * 64 + i * 16 + qr) * 64 + slot];
        bfr[i] = *(const bf16x8_t*)&sB[(wn * 64 + i * 16 + qr) * 64 + slot];
      }
      __builtin_amdgcn_s_setprio(1);
#pragma unroll
      for (int mi = 0; mi < 4; ++mi)
#pragma unroll
        for (int ni = 0; ni < 4; ++ni)
          acc[mi][ni] = MFMA16(af[mi], bfr[ni], acc[mi][ni]);
      __builtin_amdgcn_s_setprio(0);
    }
    __syncthreads();
  }

  gemm_epilogue(ga, z, epi, scl, bias, acc, m0, n0, wm, wn, qr, kg);
}

// ---------------- causal flash attention, Dk=64, QBLK=128, unpaired ---------
// Grid (8,128): 1024 blocks; bounds(256,3) -> VGPR 84 (NO spill; r12's
// bounds(256,4) capped VGPR at 64 and spilled). 3 blocks/CU resident with
// dynamic refill; jsub = 15-(y>>3) dispatches longest blocks first.
__global__ __launch_bounds__(256, 3) void attn_kernel(
    const unsigned short* __restrict__ Qp, const unsigned short* __restrict__ Kp,
    const unsigned short* __restrict__ Vt, unsigned short* __restrict__ X) {
  const int x = blockIdx.x, y = blockIdx.y;
  const int bh = x * 8 + (y & 7);
  const int jsub = 15 - (y >> 3);

  const int tid = threadIdx.x, lane = tid & 63, w = tid >> 6;
  const int qr = lane & 15, kg = lane >> 4;

  const unsigned short* Qb = Qp + (size_t)bh * Ss * DKd;
  const unsigned short* Kb = Kp + (size_t)bh * Ss * DKd;
  const unsigned short* Vb = Vt + (size_t)bh * Ss * DKd;  // [64][2048]

  __shared__ __align__(16) unsigned short kbuf[2][4096];
  __shared__ __align__(16) unsigned short vbuf[2][4096];

  const int R0 = tid >> 3, c80 = (tid & 7) ^ (R0 & 7);
  const int R1 = R0 + 32,  c81 = (tid & 7) ^ (R1 & 7);

  const int bq = bh >> 4, hh = bh & 15;

  const int qbase = jsub * 128;
  const int ntile = 2 * jsub + 2;
  const int qrowA = qbase + w * 32 + qr;
  const int qrowB = qrowA + 16;

  const bf16x8_t qfA0 = *(const bf16x8_t*)&Qb[(size_t)qrowA * DKd + kg * 8];
  const bf16x8_t qfA1 = *(const bf16x8_t*)&Qb[(size_t)qrowA * DKd + 32 + kg * 8];
  const bf16x8_t qfB0 = *(const bf16x8_t*)&Qb[(size_t)qrowB * DKd + kg * 8];
  const bf16x8_t qfB1 = *(const bf16x8_t*)&Qb[(size_t)qrowB * DKd + 32 + kg * 8];

  float lA = 0.f, lB = 0.f;
  f32x4_t o[2][4];
#pragma unroll
  for (int g = 0; g < 2; ++g)
#pragma unroll
    for (int nd = 0; nd < 4; ++nd) o[g][nd] = {0.f, 0.f, 0.f, 0.f};

  int cur = 0;
  gl16(Kb + (size_t)R0 * DKd + c80 * 8, &kbuf[0][tid * 8]);
  gl16(Kb + (size_t)R1 * DKd + c81 * 8, &kbuf[0][tid * 8 + 2048]);
  gl16(Vb + (size_t)R0 * Ss + c80 * 8, &vbuf[0][tid * 8]);
  gl16(Vb + (size_t)R1 * Ss + c81 * 8, &vbuf[0][tid * 8 + 2048]);
  __syncthreads();

  for (int t = 0; t < ntile; ++t) {
    if (t + 1 < ntile) {
      const int kv0 = (t + 1) * 64;
      const int nb = cur ^ 1;
      gl16(Kb + (size_t)(kv0 + R0) * DKd + c80 * 8, &kbuf[nb][tid * 8]);
      gl16(Kb + (size_t)(kv0 + R1) * DKd + c81 * 8, &kbuf[nb][tid * 8 + 2048]);
      gl16(Vb + (size_t)R0 * Ss + kv0 + c80 * 8, &vbuf[nb][tid * 8]);
      gl16(Vb + (size_t)R1 * Ss + kv0 + c81 * 8, &vbuf[nb][tid * 8 + 2048]);
    }

    // waves 0,1 are fully future-masked on the block's last tile
    const bool act = !(w < 2 && t == 2 * jsub + 1);
    if (act) {
      // ---- QK^T (swapped): sX[ni][j] = S[q][kv=16ni+4kg+j] - 8 ----
      f32x4_t sA_[4], sB_[4];
#pragma unroll
      for (int ni = 0; ni < 4; ++ni) {
        sA_[ni] = {-8.f, -8.f, -8.f, -8.f};
        sB_[ni] = {-8.f, -8.f, -8.f, -8.f};
      }
      __builtin_amdgcn_s_setprio(1);
#pragma unroll
      for (int ni = 0; ni < 4; ++ni) {
        const int R = ni * 16 + qr;
        const bf16x8_t kf0 =
            *(const bf16x8_t*)&kbuf[cur][(R * 8 + (kg ^ (qr & 7))) * 8];
        const bf16x8_t kf1 =
            *(const bf16x8_t*)&kbuf[cur][(R * 8 + ((4 + kg) ^ (qr & 7))) * 8];
        sA_[ni] = MFMA16(kf0, qfA0, sA_[ni]);
        sA_[ni] = MFMA16(kf1, qfA1, sA_[ni]);
        sB_[ni] = MFMA16(kf0, qfB0, sB_[ni]);
        sB_[ni] = MFMA16(kf1, qfB1, sB_[ni]);
      }
      __builtin_amdgcn_s_setprio(0);

      // ---- causal mask (last two tiles only) ----
      if (t >= 2 * jsub) {
        const int off = (t == 2 * jsub) ? 0 : 64;
        const int rA = w * 32 + qr - off;
#pragma unroll
        for (int ni = 0; ni < 4; ++ni)
#pragma unroll
          for (int j = 0; j < 4; ++j) {
            const int c = ni * 16 + kg * 4 + j;
            if (c > rA) sA_[ni][j] = -1.0e30f;
            if (c > rA + 16) sB_[ni][j] = -1.0e30f;
          }
      }

      // ---- fixed-bias softmax + pack, per group ----
      u32x2_t pbA[4], pbB[4];
#pragma unroll
      for (int ni = 0; ni < 4; ++ni) {
        float pa0 = exp2f(sA_[ni][0]), pa1 = exp2f(sA_[ni][1]);
        float pa2 = exp2f(sA_[ni][2]), pa3 = exp2f(sA_[ni][3]);
        lA += (pa0 + pa1) + (pa2 + pa3);
        bf16x2_t lo, hi;
        lo[0] = (__bf16)pa0; lo[1] = (__bf16)pa1;
        hi[0] = (__bf16)pa2; hi[1] = (__bf16)pa3;
        pbA[ni][0] = __builtin_bit_cast(unsigned, lo);
        pbA[ni][1] = __builtin_bit_cast(unsigned, hi);
        float pb0 = exp2f(sB_[ni][0]), pb1 = exp2f(sB_[ni][1]);
        float pb2 = exp2f(sB_[ni][2]), pb3 = exp2f(sB_[ni][3]);
        lB += (pb0 + pb1) + (pb2 + pb3);
        bf16x2_t lo2, hi2;
        lo2[0] = (__bf16)pb0; lo2[1] = (__bf16)pb1;
        hi2[0] = (__bf16)pb2; hi2[1] = (__bf16)pb3;
        pbB[ni][0] = __builtin_bit_cast(unsigned, lo2);
        pbB[ni][1] = __builtin_bit_cast(unsigned, hi2);
      }
      asm volatile("s_nop 1");  // VALU-write -> MFMA-read hazard guard

      // ---- PV: O^T[d][q] += V^T[d][kv] * P^T[kv][q] (k16 MFMAs) ----
      __builtin_amdgcn_s_setprio(1);
#pragma unroll
      for (int nd = 0; nd < 4; ++nd) {
        const int rb = (qr + 16 * nd) * 64 + 4 * (kg & 1);
        const int ch = kg >> 1, sw = qr & 7;
        u32x2_t va0 = *(const u32x2_t*)&vbuf[cur][rb + 8 * ((ch + 0) ^ sw)];
        u32x2_t va1 = *(const u32x2_t*)&vbuf[cur][rb + 8 * ((ch + 2) ^ sw)];
        u32x2_t va2 = *(const u32x2_t*)&vbuf[cur][rb + 8 * ((ch + 4) ^ sw)];
        u32x2_t va3 = *(const u32x2_t*)&vbuf[cur][rb + 8 * ((ch + 6) ^ sw)];
        mfma_k16(o[0][nd], va0, pbA[0]);
        mfma_k16(o[0][nd], va1, pbA[1]);
        mfma_k16(o[0][nd], va2, pbA[2]);
        mfma_k16(o[0][nd], va3, pbA[3]);
        mfma_k16(o[1][nd], va0, pbB[0]);
        mfma_k16(o[1][nd], va1, pbB[1]);
        mfma_k16(o[1][nd], va2, pbB[2]);
        mfma_k16(o[1][nd], va3, pbB[3]);
      }
      __builtin_amdgcn_s_setprio(0);
    }

    __syncthreads();  // stage(t+1) drained + all reads of buf[cur] done
    cur ^= 1;
  }

  // ---- row-sum reduce + normalize + write both groups ----
  float lsA = lA, lsB = lB;
  lsA += __shfl_xor(lsA, 16); lsA += __shfl_xor(lsA, 32);
  lsB += __shfl_xor(lsB, 16); lsB += __shfl_xor(lsB, 32);
  const float invA = 1.0f / lsA, invB = 1.0f / lsB;
#pragma unroll
  for (int nd = 0; nd < 4; ++nd) {
    u16x4_t rA, rB;
#pragma unroll
    for (int j = 0; j < 4; ++j) {
      rA[j] = f2bf(o[0][nd][j] * invA);
      rB[j] = f2bf(o[1][nd][j] * invB);
    }
    const int d = nd * 16 + kg * 4;
    *(u16x4_t*)&X[(size_t)(bq * Ss + qrowA) * DM + hh * DKd + d] = rA;
    *(u16x4_t*)&X[(size_t)(bq * Ss + qrowB) * DM + hh * DKd + d] = rB;
  }
}

// ---------------- host launch ------------------------------------------------
extern "C" void kernel_launch(void* const* d_in, const int* in_sizes, int n_in,
                              void* d_out, int out_size, void* d_ws, size_t ws_size,
                              hipStream_t stream) {
  const float* q  = (const float*)d_in[0];
  const float* k  = (const float*)d_in[1];
  const float* v  = (const float*)d_in[2];
  const float* Wq = (const float*)d_in[4];
  const float* bq = (const float*)d_in[5];
  const float* Wk = (const float*)d_in[6];
  const float* bk = (const float*)d_in[7];
  const float* Wv = (const float*)d_in[8];
  const float* bv = (const float*)d_in[9];
  const float* Wo = (const float*)d_in[10];
  const float* bo = (const float*)d_in[11];

  const size_t NIN = (size_t)Bb * Ss * DM;
  const size_t NW  = (size_t)DM * DM;

  unsigned short* ws  = (unsigned short*)d_ws;
  unsigned short* Wqb = ws;
  unsigned short* Wkb = Wqb + NW;
  unsigned short* Wvb = Wkb + NW;
  unsigned short* Wob = Wvb + NW;
  unsigned short* qb  = Wob + NW;
  unsigned short* kb  = qb + NIN;
  unsigned short* vb  = kb + NIN;
  unsigned short* Qp  = vb + NIN;
  unsigned short* Kp  = Qp + NIN;
  unsigned short* Vt  = Kp + NIN;
  unsigned short* X   = qb;  // qb dead after projections

  CvtArgs ca{};
  ca.src[0] = q;  ca.dst[0] = qb;  ca.n[0] = (int)NIN;
  ca.src[1] = k;  ca.dst[1] = kb;  ca.n[1] = (int)NIN;
  ca.src[2] = v;  ca.dst[2] = vb;  ca.n[2] = (int)NIN;
  ca.src[3] = Wq; ca.dst[3] = Wqb; ca.n[3] = (int)NW;
  ca.src[4] = Wk; ca.dst[4] = Wkb; ca.n[4] = (int)NW;
  ca.src[5] = Wv; ca.dst[5] = Wvb; ca.n[5] = (int)NW;
  ca.src[6] = Wo; ca.dst[6] = Wob; ca.n[6] = (int)NW;
  cvt_kernel<<<dim3(1024, 7), 256, 0, stream>>>(ca);

  const float SC = 0.18033688011112042f;  // (1/sqrt(64)) * log2(e)

  GemmArgs g1{};
  g1.A[0] = qb;  g1.A[1] = kb;  g1.A[2] = vb;
  g1.W[0] = Wqb; g1.W[1] = Wkb; g1.W[2] = Wvb;
  g1.bias[0] = bq; g1.bias[1] = bk; g1.bias[2] = bv;
  g1.out[0] = Qp;  g1.out[1] = Kp;  g1.out[2] = Vt;
  g1.scl[0] = SC;  g1.scl[1] = 1.f; g1.scl[2] = 1.f;
  g1.epi[0] = 0;   g1.epi[1] = 0;   g1.epi[2] = 2;
  gemm_bt<<<dim3(8, 64, 3), 256, 0, stream>>>(g1);

  attn_kernel<<<dim3(8, 128), 256, 0, stream>>>(Qp, Kp, Vt, X);

  GemmArgs g2{};
  g2.A[0] = X; g2.W[0] = Wob; g2.bias[0] = bo; g2.out[0] = d_out;
  g2.scl[0] = 1.f; g2.epi[0] = 1;
  gemm_bt<<<dim3(8, 64, 1), 256, 0, stream>>>(g2);
}

// Round 14
// 151.420 us; speedup vs baseline: 1.3435x; 1.1075x over previous
//
#include <hip/hip_runtime.h>
#include <cstdint>

#define DM   1024
#define NH   16
#define DKd  64
#define Bb   4
#define Ss   2048

using bf16x8_t = __attribute__((ext_vector_type(8))) __bf16;
using bf16x2_t = __attribute__((ext_vector_type(2))) __bf16;
using f32x4_t  = __attribute__((ext_vector_type(4))) float;
using u16x4_t  = __attribute__((ext_vector_type(4))) unsigned short;
using u16x8_t  = __attribute__((ext_vector_type(8))) unsigned short;
using u32x2_t  = __attribute__((ext_vector_type(2))) unsigned int;

#define MFMA16(a, b, c) __builtin_amdgcn_mfma_f32_16x16x32_bf16((a), (b), (c), 0, 0, 0)

// 16x16x16 bf16 MFMA via inline asm. D==C accumulate chain.
__device__ __forceinline__ void mfma_k16(f32x4_t& c, u32x2_t a, u32x2_t b) {
  asm("v_mfma_f32_16x16x16_bf16 %0, %1, %2, %0" : "+v"(c) : "v"(a), "v"(b));
}

__device__ __forceinline__ unsigned short f2bf(float f) {
  union { float f; unsigned u; } v; v.f = f;
  unsigned r = v.u + 0x7fffu + ((v.u >> 16) & 1u);
  return (unsigned short)(r >> 16);
}

__device__ __forceinline__ void gl16(const void* g, void* l) {
  __builtin_amdgcn_global_load_lds(
      (const __attribute__((address_space(1))) void*)g,
      (__attribute__((address_space(3))) void*)l, 16, 0, 0);
}

// ---------------- f32 -> bf16 conversion (q,k,v + 4 weights) -----------------
struct CvtArgs {
  const float* src[8];
  unsigned short* dst[8];
  int n[8];
};

__global__ void cvt_kernel(CvtArgs a) {
  const int seg = blockIdx.y;
  const float* __restrict__ s = a.src[seg];
  unsigned short* __restrict__ d = a.dst[seg];
  const int n = a.n[seg];
  const int step = gridDim.x * blockDim.x * 8;
  for (int i = (blockIdx.x * blockDim.x + threadIdx.x) * 8; i < n; i += step) {
    f32x4_t v0 = *(const f32x4_t*)(s + i);
    f32x4_t v1 = *(const f32x4_t*)(s + i + 4);
    u16x8_t r;
#pragma unroll
    for (int j = 0; j < 4; ++j) {
      r[j]     = f2bf(v0[j]);
      r[4 + j] = f2bf(v1[j]);
    }
    *(u16x8_t*)(d + i) = r;
  }
}

struct GemmArgs {
  const unsigned short* A[3];
  const unsigned short* W[3];
  const float* bias[3];
  void* out[3];
  float scl[3];
  int epi[3];
};

// Shared epilogue: epi 0 -> bf16 [B,H,S,64] (scaled); epi 1 -> f32 [M,N];
// epi 2 -> bf16 [B,H,64,S] (V^T).
__device__ __forceinline__ void gemm_epilogue(
    const GemmArgs& ga, int z, int epi, float scl, const float* bias,
    f32x4_t (&acc)[4][4], int m0, int n0, int wm, int wn, int qr, int kg) {
#pragma unroll
  for (int ni = 0; ni < 4; ++ni) {
    const int col = n0 + wn * 64 + ni * 16 + qr;
    const float bi = bias[col];
#pragma unroll
    for (int mi = 0; mi < 4; ++mi) {
      const int mb = m0 + wm * 64 + mi * 16 + kg * 4;
      float vv[4];
#pragma unroll
      for (int j = 0; j < 4; ++j) vv[j] = (acc[mi][ni][j] + bi) * scl;
      if (epi == 0) {
        unsigned short* O = (unsigned short*)ga.out[z];
#pragma unroll
        for (int j = 0; j < 4; ++j) {
          const int m = mb + j;
          O[(size_t)((m >> 11) * NH + (col >> 6)) * (Ss * DKd) +
            (size_t)(m & (Ss - 1)) * DKd + (col & 63)] = f2bf(vv[j]);
        }
      } else if (epi == 2) {
        unsigned short* O = (unsigned short*)ga.out[z];
        u16x4_t r;
#pragma unroll
        for (int j = 0; j < 4; ++j) r[j] = f2bf(vv[j]);
        const int b = mb >> 11, s = mb & (Ss - 1);
        *(u16x4_t*)&O[((size_t)(b * NH + (col >> 6)) * DKd + (col & 63)) * Ss + s] = r;
      } else {
        float* O = (float*)ga.out[z];
#pragma unroll
        for (int j = 0; j < 4; ++j) O[(size_t)(mb + j) * 1024 + col] = vv[j];
      }
    }
  }
}

// ---------------- bf16 GEMM: BK=64, XOR-swizzled both-sides ------------------
__global__ __launch_bounds__(256, 4) void gemm_bt(GemmArgs ga) {
  const int L = blockIdx.x + 8 * (blockIdx.y + 64 * blockIdx.z);
  const int xcd = L & 7;
  const int sidx = L >> 3;
  const int xw = sidx & 7;
  const int grp = sidx >> 3;
  const int z = grp >> 3;
  const int yw = (grp & 7) * 8 + xcd;

  const unsigned short* __restrict__ A = ga.A[z];
  const unsigned short* __restrict__ W = ga.W[z];
  const float* __restrict__ bias = ga.bias[z];
  const float scl = ga.scl[z];
  const int epi = ga.epi[z];

  __shared__ __align__(16) unsigned short sA[128 * 64];  // 16 KB
  __shared__ __align__(16) unsigned short sB[128 * 64];  // 16 KB

  const int tid  = threadIdx.x;
  const int lane = tid & 63;
  const int wid  = tid >> 6;
  const int wm   = wid >> 1, wn = wid & 1;
  const int m0 = yw * 128, n0 = xw * 128;
  const int qr = lane & 15, kg = lane >> 4;

  const int arow = tid >> 3;
  const int aswz = (tid & 7) ^ ((tid >> 3) & 7);

  f32x4_t acc[4][4];
#pragma unroll
  for (int mi = 0; mi < 4; ++mi)
#pragma unroll
    for (int ni = 0; ni < 4; ++ni) acc[mi][ni] = {0.f, 0.f, 0.f, 0.f};

  for (int kt = 0; kt < 16; ++kt) {
    const int k0 = kt * 64;
#pragma unroll
    for (int j = 0; j < 4; ++j) {
      gl16(A + (size_t)(m0 + arow + j * 32) * 1024 + k0 + aswz * 8,
           &sA[tid * 8 + j * 2048]);
      gl16(W + (size_t)(n0 + arow + j * 32) * 1024 + k0 + aswz * 8,
           &sB[tid * 8 + j * 2048]);
    }
    __syncthreads();

#pragma unroll
    for (int kk = 0; kk < 2; ++kk) {
      bf16x8_t af[4], bfr[4];
#pragma unroll
      for (int i = 0; i < 4; ++i) {
        const int slot = ((kk * 4 + kg) ^ (qr & 7)) * 8;
        af[i]  = *(const bf16x8_t*)&sA[(wm * 64 + i * 16 + qr) * 64 + slot];
        bfr[i] = *(const bf16x8_t*)&sB[(wn * 64 + i * 16 + qr) * 64 + slot];
      }
      __builtin_amdgcn_s_setprio(1);
#pragma unroll
      for (int mi = 0; mi < 4; ++mi)
#pragma unroll
        for (int ni = 0; ni < 4; ++ni)
          acc[mi][ni] = MFMA16(af[mi], bfr[ni], acc[mi][ni]);
      __builtin_amdgcn_s_setprio(0);
    }
    __syncthreads();
  }

  gemm_epilogue(ga, z, epi, scl, bias, acc, m0, n0, wm, wn, qr, kg);
}

// ---------------- causal flash attention, Dk=64, QBLK=128, unpaired ---------
// Grid (8,128), bounds(256,3). t-loop unrolled x2 (ntile always even) so the
// LDS buffer index is compile-time -> all swizzled addresses loop-invariant.
// Raw v_exp_f32 (args bounded; masked -1e30 -> exp2 = 0 exactly). Bias -8
// enters via constant MFMA C operand (no per-tile re-init movs).
__global__ __launch_bounds__(256, 3) void attn_kernel(
    const unsigned short* __restrict__ Qp, const unsigned short* __restrict__ Kp,
    const unsigned short* __restrict__ Vt, unsigned short* __restrict__ X) {
  const int x = blockIdx.x, y = blockIdx.y;
  const int bh = x * 8 + (y & 7);
  const int jsub = 15 - (y >> 3);

  const int tid = threadIdx.x, lane = tid & 63, w = tid >> 6;
  const int qr = lane & 15, kg = lane >> 4;

  const unsigned short* Qb = Qp + (size_t)bh * Ss * DKd;
  const unsigned short* Kb = Kp + (size_t)bh * Ss * DKd;
  const unsigned short* Vb = Vt + (size_t)bh * Ss * DKd;  // [64][2048]

  __shared__ __align__(16) unsigned short kbuf[2][4096];
  __shared__ __align__(16) unsigned short vbuf[2][4096];

  const int R0 = tid >> 3, c80 = (tid & 7) ^ (R0 & 7);
  const int R1 = R0 + 32,  c81 = (tid & 7) ^ (R1 & 7);

  const int bq = bh >> 4, hh = bh & 15;

  const int qbase = jsub * 128;
  const int ntile = 2 * jsub + 2;
  const int qrowA = qbase + w * 32 + qr;
  const int qrowB = qrowA + 16;

  const bf16x8_t qfA0 = *(const bf16x8_t*)&Qb[(size_t)qrowA * DKd + kg * 8];
  const bf16x8_t qfA1 = *(const bf16x8_t*)&Qb[(size_t)qrowA * DKd + 32 + kg * 8];
  const bf16x8_t qfB0 = *(const bf16x8_t*)&Qb[(size_t)qrowB * DKd + kg * 8];
  const bf16x8_t qfB1 = *(const bf16x8_t*)&Qb[(size_t)qrowB * DKd + 32 + kg * 8];

  // loop-invariant swizzled LDS element offsets
  const int sw = qr & 7, ch = kg >> 1;
  const int kbase = qr * 64;
  const int ko0 = (kg ^ sw) * 8;
  const int ko1 = ((4 + kg) ^ sw) * 8;
  const int vbase = qr * 64 + 4 * (kg & 1);
  const int vo0 = ((ch + 0) ^ sw) * 8;
  const int vo1 = ((ch + 2) ^ sw) * 8;
  const int vo2 = ((ch + 4) ^ sw) * 8;
  const int vo3 = ((ch + 6) ^ sw) * 8;

  const f32x4_t M8 = {-8.f, -8.f, -8.f, -8.f};

  float lA = 0.f, lB = 0.f;
  f32x4_t o[2][4];
#pragma unroll
  for (int g = 0; g < 2; ++g)
#pragma unroll
    for (int nd = 0; nd < 4; ++nd) o[g][nd] = {0.f, 0.f, 0.f, 0.f};

#define ASTAGE(KD, VD, KV0)                                                  \
  do {                                                                       \
    gl16(Kb + (size_t)((KV0) + R0) * DKd + c80 * 8, &(KD)[tid * 8]);         \
    gl16(Kb + (size_t)((KV0) + R1) * DKd + c81 * 8, &(KD)[tid * 8 + 2048]);  \
    gl16(Vb + (size_t)R0 * Ss + (KV0) + c80 * 8, &(VD)[tid * 8]);            \
    gl16(Vb + (size_t)R1 * Ss + (KV0) + c81 * 8, &(VD)[tid * 8 + 2048]);     \
  } while (0)

#define ATILE(KB, VB, T)                                                     \
  do {                                                                       \
    if (!(w < 2 && (T) == 2 * jsub + 1)) {                                   \
      f32x4_t sA_[4], sB_[4];                                                \
      __builtin_amdgcn_s_setprio(1);                                         \
      _Pragma("unroll") for (int ni = 0; ni < 4; ++ni) {                     \
        const bf16x8_t kf0 =                                                 \
            *(const bf16x8_t*)&(KB)[kbase + ni * 1024 + ko0];                \
        const bf16x8_t kf1 =                                                 \
            *(const bf16x8_t*)&(KB)[kbase + ni * 1024 + ko1];                \
        sA_[ni] = MFMA16(kf0, qfA0, M8);                                     \
        sA_[ni] = MFMA16(kf1, qfA1, sA_[ni]);                                \
        sB_[ni] = MFMA16(kf0, qfB0, M8);                                     \
        sB_[ni] = MFMA16(kf1, qfB1, sB_[ni]);                                \
      }                                                                      \
      __builtin_amdgcn_s_setprio(0);                                         \
      if ((T) >= 2 * jsub) {                                                 \
        const int off_ = ((T) == 2 * jsub) ? 0 : 64;                         \
        const int rA_ = w * 32 + qr - off_;                                  \
        _Pragma("unroll") for (int ni = 0; ni < 4; ++ni)                     \
          _Pragma("unroll") for (int j = 0; j < 4; ++j) {                    \
            const int c_ = ni * 16 + kg * 4 + j;                             \
            if (c_ > rA_) sA_[ni][j] = -1.0e30f;                             \
            if (c_ > rA_ + 16) sB_[ni][j] = -1.0e30f;                        \
          }                                                                  \
      }                                                                      \
      u32x2_t pbA[4], pbB[4];                                                \
      _Pragma("unroll") for (int ni = 0; ni < 4; ++ni) {                     \
        const float pa0 = __builtin_amdgcn_exp2f(sA_[ni][0]);                \
        const float pa1 = __builtin_amdgcn_exp2f(sA_[ni][1]);                \
        const float pa2 = __builtin_amdgcn_exp2f(sA_[ni][2]);                \
        const float pa3 = __builtin_amdgcn_exp2f(sA_[ni][3]);                \
        lA += (pa0 + pa1) + (pa2 + pa3);                                     \
        bf16x2_t lo_, hi_;                                                   \
        lo_[0] = (__bf16)pa0; lo_[1] = (__bf16)pa1;                          \
        hi_[0] = (__bf16)pa2; hi_[1] = (__bf16)pa3;                          \
        pbA[ni][0] = __builtin_bit_cast(unsigned, lo_);                      \
        pbA[ni][1] = __builtin_bit_cast(unsigned, hi_);                      \
        const float pb0 = __builtin_amdgcn_exp2f(sB_[ni][0]);                \
        const float pb1 = __builtin_amdgcn_exp2f(sB_[ni][1]);                \
        const float pb2 = __builtin_amdgcn_exp2f(sB_[ni][2]);                \
        const float pb3 = __builtin_amdgcn_exp2f(sB_[ni][3]);                \
        lB += (pb0 + pb1) + (pb2 + pb3);                                     \
        bf16x2_t lo2_, hi2_;                                                 \
        lo2_[0] = (__bf16)pb0; lo2_[1] = (__bf16)pb1;                        \
        hi2_[0] = (__bf16)pb2; hi2_[1] = (__bf16)pb3;                        \
        pbB[ni][0] = __builtin_bit_cast(unsigned, lo2_);                     \
        pbB[ni][1] = __builtin_bit_cast(unsigned, hi2_);                     \
      }                                                                      \
      asm volatile("s_nop 1");                                               \
      __builtin_amdgcn_s_setprio(1);                                         \
      _Pragma("unroll") for (int nd = 0; nd < 4; ++nd) {                     \
        const u32x2_t va0 =                                                  \
            *(const u32x2_t*)&(VB)[vbase + nd * 1024 + vo0];                 \
        const u32x2_t va1 =                                                  \
            *(const u32x2_t*)&(VB)[vbase + nd * 1024 + vo1];                 \
        const u32x2_t va2 =                                                  \
            *(const u32x2_t*)&(VB)[vbase + nd * 1024 + vo2];                 \
        const u32x2_t va3 =                                                  \
            *(const u32x2_t*)&(VB)[vbase + nd * 1024 + vo3];                 \
        mfma_k16(o[0][nd], va0, pbA[0]);                                     \
        mfma_k16(o[0][nd], va1, pbA[1]);                                     \
        mfma_k16(o[0][nd], va2, pbA[2]);                                     \
        mfma_k16(o[0][nd], va3, pbA[3]);                                     \
        mfma_k16(o[1][nd], va0, pbB[0]);                                     \
        mfma_k16(o[1][nd], va1, pbB[1]);                                     \
        mfma_k16(o[1][nd], va2, pbB[2]);                                     \
        mfma_k16(o[1][nd], va3, pbB[3]);                                     \
      }                                                                      \
      __builtin_amdgcn_s_setprio(0);                                         \
    }                                                                        \
  } while (0)

  ASTAGE(kbuf[0], vbuf[0], 0);
  __syncthreads();

  for (int t = 0; t < ntile; t += 2) {
    ASTAGE(kbuf[1], vbuf[1], (t + 1) * 64);  // t+1 <= ntile-1 always valid
    ATILE(kbuf[0], vbuf[0], t);
    __syncthreads();  // buf1 staged + buf0 reads done
    if (t + 2 < ntile) ASTAGE(kbuf[0], vbuf[0], (t + 2) * 64);
    ATILE(kbuf[1], vbuf[1], t + 1);
    __syncthreads();  // buf0 staged + buf1 reads done
  }
#undef ATILE
#undef ASTAGE

  // ---- row-sum reduce + normalize + write both groups ----
  float lsA = lA, lsB = lB;
  lsA += __shfl_xor(lsA, 16); lsA += __shfl_xor(lsA, 32);
  lsB += __shfl_xor(lsB, 16); lsB += __shfl_xor(lsB, 32);
  const float invA = 1.0f / lsA, invB = 1.0f / lsB;
#pragma unroll
  for (int nd = 0; nd < 4; ++nd) {
    u16x4_t rA, rB;
#pragma unroll
    for (int j = 0; j < 4; ++j) {
      rA[j] = f2bf(o[0][nd][j] * invA);
      rB[j] = f2bf(o[1][nd][j] * invB);
    }
    const int d = nd * 16 + kg * 4;
    *(u16x4_t*)&X[(size_t)(bq * Ss + qrowA) * DM + hh * DKd + d] = rA;
    *(u16x4_t*)&X[(size_t)(bq * Ss + qrowB) * DM + hh * DKd + d] = rB;
  }
}

// ---------------- host launch ------------------------------------------------
extern "C" void kernel_launch(void* const* d_in, const int* in_sizes, int n_in,
                              void* d_out, int out_size, void* d_ws, size_t ws_size,
                              hipStream_t stream) {
  const float* q  = (const float*)d_in[0];
  const float* k  = (const float*)d_in[1];
  const float* v  = (const float*)d_in[2];
  const float* Wq = (const float*)d_in[4];
  const float* bq = (const float*)d_in[5];
  const float* Wk = (const float*)d_in[6];
  const float* bk = (const float*)d_in[7];
  const float* Wv = (const float*)d_in[8];
  const float* bv = (const float*)d_in[9];
  const float* Wo = (const float*)d_in[10];
  const float* bo = (const float*)d_in[11];

  const size_t NIN = (size_t)Bb * Ss * DM;
  const size_t NW  = (size_t)DM * DM;

  unsigned short* ws  = (unsigned short*)d_ws;
  unsigned short* Wqb = ws;
  unsigned short* Wkb = Wqb + NW;
  unsigned short* Wvb = Wkb + NW;
  unsigned short* Wob = Wvb + NW;
  unsigned short* qb  = Wob + NW;
  unsigned short* kb  = qb + NIN;
  unsigned short* vb  = kb + NIN;
  unsigned short* Qp  = vb + NIN;
  unsigned short* Kp  = Qp + NIN;
  unsigned short* Vt  = Kp + NIN;
  unsigned short* X   = qb;  // qb dead after projections

  CvtArgs ca{};
  ca.src[0] = q;  ca.dst[0] = qb;  ca.n[0] = (int)NIN;
  ca.src[1] = k;  ca.dst[1] = kb;  ca.n[1] = (int)NIN;
  ca.src[2] = v;  ca.dst[2] = vb;  ca.n[2] = (int)NIN;
  ca.src[3] = Wq; ca.dst[3] = Wqb; ca.n[3] = (int)NW;
  ca.src[4] = Wk; ca.dst[4] = Wkb; ca.n[4] = (int)NW;
  ca.src[5] = Wv; ca.dst[5] = Wvb; ca.n[5] = (int)NW;
  ca.src[6] = Wo; ca.dst[6] = Wob; ca.n[6] = (int)NW;
  cvt_kernel<<<dim3(1024, 7), 256, 0, stream>>>(ca);

  const float SC = 0.18033688011112042f;  // (1/sqrt(64)) * log2(e)

  GemmArgs g1{};
  g1.A[0] = qb;  g1.A[1] = kb;  g1.A[2] = vb;
  g1.W[0] = Wqb; g1.W[1] = Wkb; g1.W[2] = Wvb;
  g1.bias[0] = bq; g1.bias[1] = bk; g1.bias[2] = bv;
  g1.out[0] = Qp;  g1.out[1] = Kp;  g1.out[2] = Vt;
  g1.scl[0] = SC;  g1.scl[1] = 1.f; g1.scl[2] = 1.f;
  g1.epi[0] = 0;   g1.epi[1] = 0;   g1.epi[2] = 2;
  gemm_bt<<<dim3(8, 64, 3), 256, 0, stream>>>(g1);

  attn_kernel<<<dim3(8, 128), 256, 0, stream>>>(Qp, Kp, Vt, X);

  GemmArgs g2{};
  g2.A[0] = X; g2.W[0] = Wob; g2.bias[0] = bo; g2.out[0] = d_out;
  g2.scl[0] = 1.f; g2.epi[0] = 1;
  gemm_bt<<<dim3(8, 64, 1), 256, 0, stream>>>(g2);
}